// Round 7
// baseline (222.012 us; speedup 1.0000x reference)
//
#include <hip/hip_runtime.h>

#define N_NODES  100000
#define N_EDGES  1600000
#define N_GRAPHS 256
#define F        64

// ---------------------------------------------------------------------------
// R24. Evidence chain:
//  - R6: cooperative fusion PASSED but 213us vs split 179us: grid.sync spin
//    (fused dispatch 1130us under rocprof, VALUBusy 3.8%) + lost cross-phase
//    overlap. Fusion abandoned with data.
//  - R0..R4: gather 80us, VALUBusy 47% = ~38us VALU issue; per-node cost is
//    dominated by FIXED cross-lane work (24-shfl reduce + 64-readlane matmul),
//    not the memory gather.  -> lane=feature gather (no reduce) + MFMA
//    transform (hi/lo bf16 split preserves ~f32 accuracy).
//  - R3: random 4B global writes cost a 64B line each -> scatter stays
//    LDS-staged/block-local (bin/sortcast kept verbatim from R6-verified code).
//  - R1: no min-waves launch bound (VGPR cap -> spill disaster).
// Pipeline: memset(balloc) -> bin(1024) -> sortcast(1024, +zero out/denom)
//           -> gather_mfma(1563) -> fin(64).
// ---------------------------------------------------------------------------

#define GRID_PRE 1024
#define BLK      256

#define NBUCK    196          // buckets of 512 nodes (dst >> 9)
#define BCAP     9216         // mean 8163, sigma ~90 -> +11.6 sigma
#define BSTRIDE  16           // balloc: one counter per 64B line
#define EPB      1563         // ceil(N_EDGES / GRID_PRE)
#define REPT     7            // ceil(EPB / BLK)

#define CAST_ELEMS (N_NODES * F / 4)     // 1,600,000 float4
#define NT_BLOCKS  ((N_NODES + 63) / 64) // 1563 blocks, 64 nodes each

typedef short  bf16x8 __attribute__((ext_vector_type(8)));
typedef float  f32x4  __attribute__((ext_vector_type(4)));

__device__ __forceinline__ unsigned short f2bf(float f) {
    unsigned int u = __float_as_uint(f);
    u += 0x7FFFu + ((u >> 16) & 1u);
    return (unsigned short)(u >> 16);
}
__device__ __forceinline__ float bfu(unsigned short u) {
    return __uint_as_float((unsigned)u << 16);
}

// ---------- K1: bin edges into bucket-contiguous runs (R6-verified body) ----------
__global__ __launch_bounds__(BLK) void bin_kernel(
        const int* __restrict__ src, const int* __restrict__ dst,
        unsigned int* __restrict__ pairs, int* __restrict__ balloc) {
    __shared__ int hist[NBUCK], roffs[NBUCK], bbase[NBUCK], curs[NBUCK];
    __shared__ int wsum[8];
    __shared__ unsigned int   stage[EPB];
    __shared__ unsigned short bstage[EPB];
    int tid = threadIdx.x, bid = blockIdx.x;
    int lane = tid & 63, wv = tid >> 6;
    int base = bid * EPB;
    int m = min(EPB, N_EDGES - base);

    for (int k = tid; k < NBUCK; k += BLK) hist[k] = 0;
    __syncthreads();

    int de[REPT], se[REPT];
    #pragma unroll
    for (int r = 0; r < REPT; ++r) {
        int e = tid + r * BLK;
        if (e < m) {
            de[r] = dst[base + e];
            se[r] = src[base + e];
            atomicAdd(&hist[de[r] >> 9], 1);
        } else { de[r] = -1; se[r] = 0; }
    }
    __syncthreads();

    int cnt = (tid < NBUCK) ? hist[tid] : 0;
    int v = cnt;
    #pragma unroll
    for (int o = 1; o < 64; o <<= 1) { int u = __shfl_up(v, o, 64); if (lane >= o) v += u; }
    if (lane == 63) wsum[wv] = v;
    __syncthreads();
    if (tid < 4) {
        int sv = wsum[tid];
        int u = __shfl_up(sv, 1, 64); if (tid >= 1) sv += u;
        u     = __shfl_up(sv, 2, 64); if (tid >= 2) sv += u;
        wsum[tid] = sv;
    }
    __syncthreads();
    if (wv > 0) v += wsum[wv - 1];
    if (tid < NBUCK) {
        int excl = v - cnt;
        roffs[tid] = excl;
        curs[tid]  = excl;
        bbase[tid] = tid * BCAP + atomicAdd(&balloc[tid * BSTRIDE], cnt);
    }
    __syncthreads();

    #pragma unroll
    for (int r = 0; r < REPT; ++r) {
        if (de[r] >= 0) {
            int bk  = de[r] >> 9;
            int pos = atomicAdd(&curs[bk], 1);
            stage[pos]  = ((unsigned)(de[r] & 511) << 17) | (unsigned)se[r];
            bstage[pos] = (unsigned short)bk;
        }
    }
    __syncthreads();
    for (int e = tid; e < m; e += BLK) {
        int bk = bstage[e];
        pairs[bbase[bk] + (e - roffs[bk])] = stage[e];
    }
}

// ---------- K2: per-bucket node sort | cast | zero (R6-verified body + zero) ----------
__global__ __launch_bounds__(BLK) void sortcast_kernel(
        const float* __restrict__ x, unsigned short* __restrict__ xh,
        const unsigned int* __restrict__ pairs, int* __restrict__ eidx,
        int* __restrict__ nbeg, int* __restrict__ nend,
        const int* __restrict__ balloc,
        float* __restrict__ out, float* __restrict__ denom) {
    __shared__ int hist[512], curs[512], wsum[8];
    int tid = threadIdx.x, bid = blockIdx.x;
    int lane = tid & 63, wv = tid >> 6;

    if (bid < NBUCK) {
        int E     = balloc[bid * BSTRIDE];
        int base  = bid * BCAP;
        int node0 = bid << 9;
        int nn    = min(512, N_NODES - node0);

        hist[tid] = 0; hist[tid + 256] = 0;
        __syncthreads();
        for (int i = tid; i < E; i += BLK)
            atomicAdd(&hist[pairs[base + i] >> 17], 1);
        __syncthreads();

        int c0 = hist[tid];
        int v0 = c0;
        #pragma unroll
        for (int o = 1; o < 64; o <<= 1) { int u = __shfl_up(v0, o, 64); if (lane >= o) v0 += u; }
        if (lane == 63) wsum[wv] = v0;
        __syncthreads();
        if (tid < 4) {
            int sv = wsum[tid];
            int u = __shfl_up(sv, 1, 64); if (tid >= 1) sv += u;
            u     = __shfl_up(sv, 2, 64); if (tid >= 2) sv += u;
            wsum[tid] = sv;
        }
        __syncthreads();
        if (wv > 0) v0 += wsum[wv - 1];
        int total0 = wsum[3];

        int c1 = hist[tid + 256];
        int v1 = c1;
        #pragma unroll
        for (int o = 1; o < 64; o <<= 1) { int u = __shfl_up(v1, o, 64); if (lane >= o) v1 += u; }
        if (lane == 63) wsum[4 + wv] = v1;
        __syncthreads();
        if (tid < 4) {
            int sv = wsum[4 + tid];
            int u = __shfl_up(sv, 1, 64); if (tid >= 1) sv += u;
            u     = __shfl_up(sv, 2, 64); if (tid >= 2) sv += u;
            wsum[4 + tid] = sv;
        }
        __syncthreads();
        if (wv > 0) v1 += wsum[4 + wv - 1];
        v1 += total0;

        int e0 = v0 - c0, e1 = v1 - c1;
        curs[tid] = e0; curs[tid + 256] = e1;
        if (tid < nn)       { nbeg[node0 + tid] = base + e0;
                              nend[node0 + tid] = base + e0 + c0; }
        if (tid + 256 < nn) { nbeg[node0 + tid + 256] = base + e1;
                              nend[node0 + tid + 256] = base + e1 + c1; }
        __syncthreads();

        for (int i = tid; i < E; i += BLK) {
            unsigned int p = pairs[base + i];
            int pos = atomicAdd(&curs[p >> 17], 1);
            eidx[base + pos] = (int)(p & 0x1FFFFu);
        }
    } else {
        if (bid == NBUCK) {   // first cast block also zeros out/denom
            for (int i = tid; i < N_GRAPHS * F; i += BLK) out[i] = 0.f;
            denom[tid] = 0.f;
        }
        int i0      = (bid - NBUCK) * BLK + tid;
        int cstride = (GRID_PRE - NBUCK) * BLK;
        for (int i = i0; i < CAST_ELEMS; i += cstride) {
            float4 v4 = ((const float4*)x)[i];
            ushort4 o;
            o.x = f2bf(v4.x); o.y = f2bf(v4.y); o.z = f2bf(v4.z); o.w = f2bf(v4.w);
            ((ushort4*)xh)[i] = o;
        }
    }
}

// ---------- K3: lane=feature gather + MFMA transform + attention pool ----------
// Block = 4 waves x 16 nodes = 64 nodes. Per wave: gather its 16 nodes with
// lane=feature (coalesced 128B row loads, NO cross-lane reduce), write hi/lo
// bf16 y-rows to its own LDS A-tile (wave-synchronous, no barrier), then
// 16 MFMAs (hi+lo) against W staged transposed in LDS. Epilogue: scores via
// 4-round shfl reduce, unshifted exp, per-graph pooling via 2-round shfl +
// a handful of atomics. C layout (HW-verified): col=lane&15, row=4*(l>>4)+r.
__global__ __launch_bounds__(BLK) void gather_mfma_kernel(
        const unsigned short* __restrict__ xh,
        const int*   __restrict__ nbeg,
        const int*   __restrict__ nend,
        const int*   __restrict__ eidx,
        const int*   __restrict__ batch,
        const float* __restrict__ Wg,   // [64,64] (k, f)
        const float* __restrict__ bg,
        const float* __restrict__ Wa,
        const float* __restrict__ ba,
        float*       __restrict__ out,
        float*       __restrict__ denom) {
    __shared__ unsigned short shAhi[64 * 64];   // 8 KB
    __shared__ unsigned short shAlo[64 * 64];   // 8 KB
    __shared__ unsigned short shW[64 * 64];     // 8 KB, Wt[n][k]

    int tid  = threadIdx.x;
    int bid  = blockIdx.x;
    int lane = tid & 63;
    int w    = tid >> 6;

    // stage W transposed as bf16: shW[n*64+k] = bf16(Wg[k*64+n])
    for (int i = tid; i < 64 * 64; i += BLK) {
        int k = i >> 6, n = i & 63;
        shW[n * 64 + k] = f2bf(Wg[i]);
    }
    __syncthreads();   // only block-wide barrier

    int tile_base = bid * 64 + w * 16;
    if (tile_base >= N_NODES) return;   // idle tail waves (no later barriers)

    // ---- gather phase: lane = feature ----
    int nb = 0, ne = 0;
    {
        int nd = tile_base + lane;
        if (lane < 16 && nd < N_NODES) { nb = nbeg[nd]; ne = nend[nd]; }
    }
    int pb_c = __builtin_amdgcn_readlane(nb, 0);
    int pe_c = __builtin_amdgcn_readlane(ne, 0);
    int sl_c = (pb_c + lane < pe_c) ? eidx[pb_c + lane] : 0;

    for (int q = 0; q < 16; ++q) {
        int node = tile_base + q;
        int pb = pb_c, pe = pe_c, sl = sl_c;
        if (q + 1 < 16) {   // prefetch next node's first edge chunk
            pb_c = __builtin_amdgcn_readlane(nb, q + 1);
            pe_c = __builtin_amdgcn_readlane(ne, q + 1);
            sl_c = (pb_c + lane < pe_c) ? eidx[pb_c + lane] : 0;
        }
        float y = 0.f;
        if (node < N_NODES) {
            y = bfu(xh[node * 64 + lane]);          // self row
            int c0 = min(pe - pb, 64);
            int e = 0;
            for (; e + 8 <= c0; e += 8) {
                int i0 = __builtin_amdgcn_readlane(sl, e + 0);
                int i1 = __builtin_amdgcn_readlane(sl, e + 1);
                int i2 = __builtin_amdgcn_readlane(sl, e + 2);
                int i3 = __builtin_amdgcn_readlane(sl, e + 3);
                int i4 = __builtin_amdgcn_readlane(sl, e + 4);
                int i5 = __builtin_amdgcn_readlane(sl, e + 5);
                int i6 = __builtin_amdgcn_readlane(sl, e + 6);
                int i7 = __builtin_amdgcn_readlane(sl, e + 7);
                float v0 = bfu(xh[i0 * 64 + lane]);
                float v1 = bfu(xh[i1 * 64 + lane]);
                float v2 = bfu(xh[i2 * 64 + lane]);
                float v3 = bfu(xh[i3 * 64 + lane]);
                float v4 = bfu(xh[i4 * 64 + lane]);
                float v5 = bfu(xh[i5 * 64 + lane]);
                float v6 = bfu(xh[i6 * 64 + lane]);
                float v7 = bfu(xh[i7 * 64 + lane]);
                y += ((v0 + v1) + (v2 + v3)) + ((v4 + v5) + (v6 + v7));
            }
            for (; e < c0; ++e) {
                int i0 = __builtin_amdgcn_readlane(sl, e);
                y += bfu(xh[i0 * 64 + lane]);
            }
            for (int b2 = pb + 64; b2 < pe; b2 += 64) {   // rare deg > 64
                int sl2 = (b2 + lane < pe) ? eidx[b2 + lane] : 0;
                int c2 = min(pe - b2, 64);
                int e2 = 0;
                for (; e2 + 8 <= c2; e2 += 8) {
                    int i0 = __builtin_amdgcn_readlane(sl2, e2 + 0);
                    int i1 = __builtin_amdgcn_readlane(sl2, e2 + 1);
                    int i2 = __builtin_amdgcn_readlane(sl2, e2 + 2);
                    int i3 = __builtin_amdgcn_readlane(sl2, e2 + 3);
                    int i4 = __builtin_amdgcn_readlane(sl2, e2 + 4);
                    int i5 = __builtin_amdgcn_readlane(sl2, e2 + 5);
                    int i6 = __builtin_amdgcn_readlane(sl2, e2 + 6);
                    int i7 = __builtin_amdgcn_readlane(sl2, e2 + 7);
                    float v0 = bfu(xh[i0 * 64 + lane]);
                    float v1 = bfu(xh[i1 * 64 + lane]);
                    float v2 = bfu(xh[i2 * 64 + lane]);
                    float v3 = bfu(xh[i3 * 64 + lane]);
                    float v4 = bfu(xh[i4 * 64 + lane]);
                    float v5 = bfu(xh[i5 * 64 + lane]);
                    float v6 = bfu(xh[i6 * 64 + lane]);
                    float v7 = bfu(xh[i7 * 64 + lane]);
                    y += ((v0 + v1) + (v2 + v3)) + ((v4 + v5) + (v6 + v7));
                }
                for (; e2 < c2; ++e2) {
                    int i0 = __builtin_amdgcn_readlane(sl2, e2);
                    y += bfu(xh[i0 * 64 + lane]);
                }
            }
        }
        // hi/lo bf16 split: A_hi + A_lo reproduces y to ~f32 accuracy
        unsigned short hh = f2bf(y);
        float lo = y - bfu(hh);
        unsigned short hl = f2bf(lo);
        shAhi[(w * 16 + q) * 64 + lane] = hh;
        shAlo[(w * 16 + q) * 64 + lane] = hl;
    }

    // ---- MFMA phase: H(16x64) = (Ahi+Alo)(16x64) @ W(64x64), per wave ----
    int lr = lane & 15, lq = lane >> 4;
    // A frags: A[m][k], m=lane&15, k=32*s + 8*(lane>>4) + i
    const bf16x8 ah0 = *(const bf16x8*)&shAhi[(w * 16 + lr) * 64 +  0 + 8 * lq];
    const bf16x8 ah1 = *(const bf16x8*)&shAhi[(w * 16 + lr) * 64 + 32 + 8 * lq];
    const bf16x8 al0 = *(const bf16x8*)&shAlo[(w * 16 + lr) * 64 +  0 + 8 * lq];
    const bf16x8 al1 = *(const bf16x8*)&shAlo[(w * 16 + lr) * 64 + 32 + 8 * lq];

    f32x4 acc0 = {0.f,0.f,0.f,0.f}, acc1 = {0.f,0.f,0.f,0.f};
    f32x4 acc2 = {0.f,0.f,0.f,0.f}, acc3 = {0.f,0.f,0.f,0.f};
    // B frags from Wt[n][k]: n=16*t+(lane&15), k=32*s + 8*(lane>>4) + i
    #define DO_TILE(t, accv) { \
        bf16x8 b0 = *(const bf16x8*)&shW[(16*(t) + lr) * 64 +  0 + 8 * lq]; \
        bf16x8 b1 = *(const bf16x8*)&shW[(16*(t) + lr) * 64 + 32 + 8 * lq]; \
        accv = __builtin_amdgcn_mfma_f32_16x16x32_bf16(ah0, b0, accv, 0, 0, 0); \
        accv = __builtin_amdgcn_mfma_f32_16x16x32_bf16(al0, b0, accv, 0, 0, 0); \
        accv = __builtin_amdgcn_mfma_f32_16x16x32_bf16(ah1, b1, accv, 0, 0, 0); \
        accv = __builtin_amdgcn_mfma_f32_16x16x32_bf16(al1, b1, accv, 0, 0, 0); }
    DO_TILE(0, acc0) DO_TILE(1, acc1) DO_TILE(2, acc2) DO_TILE(3, acc3)
    #undef DO_TILE

    // ---- epilogue: bias+relu, scores, unshifted exp, per-graph pooling ----
    float bg0 = bg[lr], bg1 = bg[16 + lr], bg2 = bg[32 + lr], bg3 = bg[48 + lr];
    float wa0 = Wa[lr], wa1 = Wa[16 + lr], wa2 = Wa[32 + lr], wa3 = Wa[48 + lr];
    float ba0 = ba[0];

    float hv0[4], hv1[4], hv2[4], hv3[4];   // [t][r]: h[4*lq+r][16t+lr]
    #pragma unroll
    for (int r = 0; r < 4; ++r) {
        hv0[r] = fmaxf(acc0[r] + bg0, 0.f);
        hv1[r] = fmaxf(acc1[r] + bg1, 0.f);
        hv2[r] = fmaxf(acc2[r] + bg2, 0.f);
        hv3[r] = fmaxf(acc3[r] + bg3, 0.f);
    }
    float part[4];
    #pragma unroll
    for (int r = 0; r < 4; ++r)
        part[r] = hv0[r] * wa0 + hv1[r] * wa1 + hv2[r] * wa2 + hv3[r] * wa3;
    #pragma unroll
    for (int o = 1; o <= 8; o <<= 1) {
        #pragma unroll
        for (int r = 0; r < 4; ++r) part[r] += __shfl_xor(part[r], o, 64);
    }
    float ev[4]; int gidx[4];
    #pragma unroll
    for (int r = 0; r < 4; ++r) {
        int node = tile_base + 4 * lq + r;
        bool ok = node < N_NODES;
        ev[r]   = ok ? __expf(part[r] + ba0) : 0.f;   // unshifted exp (proven)
        gidx[r] = ok ? batch[node] : 0;
    }
    int gmin = batch[tile_base];
    int glast = tile_base + 15; if (glast >= N_NODES) glast = N_NODES - 1;
    int gmax = batch[glast];

    for (int gg = gmin; gg <= gmax; ++gg) {
        float w0 = (gidx[0] == gg) ? ev[0] : 0.f;
        float w1 = (gidx[1] == gg) ? ev[1] : 0.f;
        float w2 = (gidx[2] == gg) ? ev[2] : 0.f;
        float w3 = (gidx[3] == gg) ? ev[3] : 0.f;
        float p0 = w0 * hv0[0] + w1 * hv0[1] + w2 * hv0[2] + w3 * hv0[3];
        float p1 = w0 * hv1[0] + w1 * hv1[1] + w2 * hv1[2] + w3 * hv1[3];
        float p2 = w0 * hv2[0] + w1 * hv2[1] + w2 * hv2[2] + w3 * hv2[3];
        float p3 = w0 * hv3[0] + w1 * hv3[1] + w2 * hv3[2] + w3 * hv3[3];
        float dn = w0 + w1 + w2 + w3;
        #pragma unroll
        for (int o = 16; o <= 32; o <<= 1) {
            p0 += __shfl_xor(p0, o, 64); p1 += __shfl_xor(p1, o, 64);
            p2 += __shfl_xor(p2, o, 64); p3 += __shfl_xor(p3, o, 64);
            dn += __shfl_xor(dn, o, 64);
        }
        if (lq == 0) {
            atomicAdd(&out[gg * F +  0 + lr], p0);
            atomicAdd(&out[gg * F + 16 + lr], p1);
            atomicAdd(&out[gg * F + 32 + lr], p2);
            atomicAdd(&out[gg * F + 48 + lr], p3);
            if (lr == 0) atomicAdd(&denom[gg], dn);
        }
    }
}

// ---------- K4: out /= denom ----------
__global__ __launch_bounds__(BLK) void fin_kernel(
        float* __restrict__ out, const float* __restrict__ denom) {
    int i = blockIdx.x * BLK + threadIdx.x;
    if (i >= N_GRAPHS * F) return;
    float d = denom[i >> 6];
    out[i] = (d > 0.f) ? out[i] / d : 0.f;
}

extern "C" void kernel_launch(void* const* d_in, const int* in_sizes, int n_in,
                              void* d_out, int out_size, void* d_ws, size_t ws_size,
                              hipStream_t stream) {
    const float* x     = (const float*)d_in[0];
    const int*   ei    = (const int*)d_in[1];   // [2, N_EDGES]
    const int*   batch = (const int*)d_in[2];   // [N_NODES]
    const float* Wg    = (const float*)d_in[3];
    const float* bg    = (const float*)d_in[4];
    const float* Wa    = (const float*)d_in[5];
    const float* ba    = (const float*)d_in[6];
    float* out = (float*)d_out;

    const int* src = ei;
    const int* dst = ei + N_EDGES;

    // workspace layout (bytes), ~28.07 MB
    char* ws = (char*)d_ws;
    unsigned short* xh     = (unsigned short*)(ws);            // 12,800,000
    unsigned int*   pairs  = (unsigned int*)(ws + 12800000);   //  7,225,344
    int*            eidx   = (int*)(ws + 20025344);            //  7,225,344
    int*            nbeg   = (int*)(ws + 27250688);            //    400,000
    int*            nend   = (int*)(ws + 27652096);            //    400,000
    int*            balloc = (int*)(ws + 28053504);            //     12,544
    float*          denom  = (float*)(ws + 28066048);          //      1,024

    hipMemsetAsync(balloc, 0, NBUCK * BSTRIDE * sizeof(int), stream);
    bin_kernel      <<<GRID_PRE, BLK, 0, stream>>>(src, dst, pairs, balloc);
    sortcast_kernel <<<GRID_PRE, BLK, 0, stream>>>(x, xh, pairs, eidx,
                                                   nbeg, nend, balloc, out, denom);
    gather_mfma_kernel<<<NT_BLOCKS, BLK, 0, stream>>>(xh, nbeg, nend, eidx, batch,
                                                      Wg, bg, Wa, ba, out, denom);
    fin_kernel      <<<64, BLK, 0, stream>>>(out, denom);
}

// Round 8
// 219.930 us; speedup vs baseline: 1.0095x; 1.0095x over previous
//
#include <hip/hip_runtime.h>

#define N_NODES  100000
#define N_EDGES  1600000
#define N_GRAPHS 256
#define F        64

// ---------------------------------------------------------------------------
// R25. Evidence chain:
//  - R7: MFMA path correct (absmax 0.0625) but gather_mfma 88.5us with
//    7.1M LDS bank conflicts (shW transpose staging: 128B row stride -> all
//    lanes bank 0) and ~1.7M tiny 2B/lane row loads (17 vmem/node) ->
//    vmcnt-latency-bound (VALUBusy fell 47->27%).
//    Fix: 72-ushort (144B) padded LDS rows; uint2 gather = 4 edges/load.
//  - R6: cooperative fusion 213us vs split 179us (grid.sync spin) - dead end.
//  - R4: prep ~99us; sortcast's 196 buckets x 256thr was the serial tail ->
//    512 threads now.
//  - R3: random 4B global writes cost a 64B line each -> scatter stays
//    LDS-staged/block-local.  - R1: no min-waves VGPR cap.
// ---------------------------------------------------------------------------

#define GRID_PRE 1024
#define BLK      256
#define SBLK     512

#define NBUCK    196          // buckets of 512 nodes (dst >> 9)
#define BCAP     9216         // mean 8163, sigma ~90 -> +11.6 sigma
#define BSTRIDE  16           // balloc: one counter per 64B line
#define EPB      1563         // ceil(N_EDGES / GRID_PRE)
#define REPT     7            // ceil(EPB / BLK)

#define CAST_ELEMS (N_NODES * F / 4)     // 1,600,000 float4
#define NT_BLOCKS  ((N_NODES + 63) / 64) // 1563 blocks, 64 nodes each

#define AST 72   // padded LDS row stride (ushorts): 144 B, 16B-aligned, bank+4/row

typedef short  bf16x8 __attribute__((ext_vector_type(8)));
typedef float  f32x4  __attribute__((ext_vector_type(4)));

__device__ __forceinline__ unsigned short f2bf(float f) {
    unsigned int u = __float_as_uint(f);
    u += 0x7FFFu + ((u >> 16) & 1u);
    return (unsigned short)(u >> 16);
}
__device__ __forceinline__ float bfu(unsigned short u) {
    return __uint_as_float((unsigned)u << 16);
}

// ---------- K1: bin edges into bucket-contiguous runs (R6/R7-verified) ----------
__global__ __launch_bounds__(BLK) void bin_kernel(
        const int* __restrict__ src, const int* __restrict__ dst,
        unsigned int* __restrict__ pairs, int* __restrict__ balloc) {
    __shared__ int hist[NBUCK], roffs[NBUCK], bbase[NBUCK], curs[NBUCK];
    __shared__ int wsum[8];
    __shared__ unsigned int   stage[EPB];
    __shared__ unsigned short bstage[EPB];
    int tid = threadIdx.x, bid = blockIdx.x;
    int lane = tid & 63, wv = tid >> 6;
    int base = bid * EPB;
    int m = min(EPB, N_EDGES - base);

    for (int k = tid; k < NBUCK; k += BLK) hist[k] = 0;
    __syncthreads();

    int de[REPT], se[REPT];
    #pragma unroll
    for (int r = 0; r < REPT; ++r) {
        int e = tid + r * BLK;
        if (e < m) {
            de[r] = dst[base + e];
            se[r] = src[base + e];
            atomicAdd(&hist[de[r] >> 9], 1);
        } else { de[r] = -1; se[r] = 0; }
    }
    __syncthreads();

    int cnt = (tid < NBUCK) ? hist[tid] : 0;
    int v = cnt;
    #pragma unroll
    for (int o = 1; o < 64; o <<= 1) { int u = __shfl_up(v, o, 64); if (lane >= o) v += u; }
    if (lane == 63) wsum[wv] = v;
    __syncthreads();
    if (tid < 4) {
        int sv = wsum[tid];
        int u = __shfl_up(sv, 1, 64); if (tid >= 1) sv += u;
        u     = __shfl_up(sv, 2, 64); if (tid >= 2) sv += u;
        wsum[tid] = sv;
    }
    __syncthreads();
    if (wv > 0) v += wsum[wv - 1];
    if (tid < NBUCK) {
        int excl = v - cnt;
        roffs[tid] = excl;
        curs[tid]  = excl;
        bbase[tid] = tid * BCAP + atomicAdd(&balloc[tid * BSTRIDE], cnt);
    }
    __syncthreads();

    #pragma unroll
    for (int r = 0; r < REPT; ++r) {
        if (de[r] >= 0) {
            int bk  = de[r] >> 9;
            int pos = atomicAdd(&curs[bk], 1);
            stage[pos]  = ((unsigned)(de[r] & 511) << 17) | (unsigned)se[r];
            bstage[pos] = (unsigned short)bk;
        }
    }
    __syncthreads();
    for (int e = tid; e < m; e += BLK) {
        int bk = bstage[e];
        pairs[bbase[bk] + (e - roffs[bk])] = stage[e];
    }
}

// ---------- K2: per-bucket node sort | cast | zero (512 threads) ----------
__global__ __launch_bounds__(SBLK) void sortcast_kernel(
        const float* __restrict__ x, unsigned short* __restrict__ xh,
        const unsigned int* __restrict__ pairs, int* __restrict__ eidx,
        int* __restrict__ nbeg, int* __restrict__ nend,
        const int* __restrict__ balloc,
        float* __restrict__ out, float* __restrict__ denom) {
    __shared__ int hist[512], curs[512], wsum[8];
    int tid = threadIdx.x, bid = blockIdx.x;
    int lane = tid & 63, wv = tid >> 6;   // 8 waves

    if (bid < NBUCK) {
        int E     = balloc[bid * BSTRIDE];
        int base  = bid * BCAP;
        int node0 = bid << 9;
        int nn    = min(512, N_NODES - node0);

        hist[tid] = 0;
        __syncthreads();
        for (int i = tid; i < E; i += SBLK)
            atomicAdd(&hist[pairs[base + i] >> 17], 1);
        __syncthreads();

        int c = hist[tid];
        int v = c;
        #pragma unroll
        for (int o = 1; o < 64; o <<= 1) { int u = __shfl_up(v, o, 64); if (lane >= o) v += u; }
        if (lane == 63) wsum[wv] = v;
        __syncthreads();
        if (tid < 8) {
            int sv = wsum[tid];
            int u = __shfl_up(sv, 1, 64); if (tid >= 1) sv += u;
            u     = __shfl_up(sv, 2, 64); if (tid >= 2) sv += u;
            u     = __shfl_up(sv, 4, 64); if (tid >= 4) sv += u;
            wsum[tid] = sv;
        }
        __syncthreads();
        if (wv > 0) v += wsum[wv - 1];

        int excl = v - c;
        curs[tid] = excl;
        if (tid < nn) {
            nbeg[node0 + tid] = base + excl;
            nend[node0 + tid] = base + excl + c;
        }
        __syncthreads();

        // scatter confined to this block's own 36KB region: lines merge in L2
        for (int i = tid; i < E; i += SBLK) {
            unsigned int p = pairs[base + i];
            int pos = atomicAdd(&curs[p >> 17], 1);
            eidx[base + pos] = (int)(p & 0x1FFFFu);
        }
    } else {
        if (bid == NBUCK) {   // first cast block also zeros out/denom
            for (int i = tid; i < N_GRAPHS * F; i += SBLK) out[i] = 0.f;
            if (tid < N_GRAPHS) denom[tid] = 0.f;
        }
        int i0      = (bid - NBUCK) * SBLK + tid;
        int cstride = (GRID_PRE - NBUCK) * SBLK;
        for (int i = i0; i < CAST_ELEMS; i += cstride) {
            float4 v4 = ((const float4*)x)[i];
            ushort4 o;
            o.x = f2bf(v4.x); o.y = f2bf(v4.y); o.z = f2bf(v4.z); o.w = f2bf(v4.w);
            ((ushort4*)xh)[i] = o;
        }
    }
}

// ---------- K3: uint2 gather + MFMA transform + attention pool ----------
// Block = 4 waves x 16 nodes. Gather: lg=lane>>4 (edge slot in quad),
// li=lane&15 (col quad: features 4li..4li+3). 4 edges per uint2 load,
// 2-round shfl_xor(16,32) reduce per node. LDS rows padded to AST=72
// ushorts (R7's 7.1M bank conflicts were the unpadded 128B stride).
// MFMA layouts proven in R7 (absmax 0.0625). Epilogue unchanged.
__global__ __launch_bounds__(BLK) void gather_mfma_kernel(
        const unsigned short* __restrict__ xh,
        const int*   __restrict__ nbeg,
        const int*   __restrict__ nend,
        const int*   __restrict__ eidx,
        const int*   __restrict__ batch,
        const float* __restrict__ Wg,   // [64,64] (k, f)
        const float* __restrict__ bg,
        const float* __restrict__ Wa,
        const float* __restrict__ ba,
        float*       __restrict__ out,
        float*       __restrict__ denom) {
    __shared__ unsigned short shAhi[64 * AST];   // 9216 B
    __shared__ unsigned short shAlo[64 * AST];   // 9216 B
    __shared__ unsigned short shW[64 * AST];     // 9216 B, Wt[n][k]

    int tid  = threadIdx.x;
    int bid  = blockIdx.x;
    int lane = tid & 63;
    int w    = tid >> 6;

    // stage W transposed as bf16: shW[n*AST+k] = bf16(Wg[k*64+n])
    // padded stride -> 4-way conflict on stores (was 32-way), free on reads
    for (int i = tid; i < 64 * 64; i += BLK) {
        int k = i >> 6, n = i & 63;
        shW[n * AST + k] = f2bf(Wg[i]);
    }
    __syncthreads();   // only block-wide barrier

    int tile_base = bid * 64 + w * 16;
    if (tile_base >= N_NODES) return;   // idle tail waves (no later barriers)

    int li = lane & 15;     // col quad
    int lg = lane >> 4;     // edge slot within a quad of edges

    const uint2* xh2 = (const uint2*)xh;    // row = 16 uint2

    // per-node run bounds for this wave's 16 nodes (lanes 0..15)
    int nb = 0, ne = 0;
    {
        int nd = tile_base + lane;
        if (lane < 16 && nd < N_NODES) { nb = nbeg[nd]; ne = nend[nd]; }
    }
    int pb_c = __builtin_amdgcn_readlane(nb, 0);
    int pe_c = __builtin_amdgcn_readlane(ne, 0);
    int sl_c = (pb_c + lane < pe_c) ? eidx[pb_c + lane] : 0;

    for (int q = 0; q < 16; ++q) {
        int node = tile_base + q;
        int pb = pb_c, pe = pe_c, sl = sl_c;
        if (q + 1 < 16) {   // prefetch next node's first edge chunk
            pb_c = __builtin_amdgcn_readlane(nb, q + 1);
            pe_c = __builtin_amdgcn_readlane(ne, q + 1);
            sl_c = (pb_c + lane < pe_c) ? eidx[pb_c + lane] : 0;
        }
        float y0 = 0.f, y1 = 0.f, y2 = 0.f, y3 = 0.f;
        if (node < N_NODES) {
            {   // self row: one wave instruction, counted once via lg==0
                uint2 v = xh2[node * 16 + li];
                if (lg == 0) {
                    y0 += __uint_as_float(v.x << 16);
                    y1 += __uint_as_float(v.x & 0xFFFF0000u);
                    y2 += __uint_as_float(v.y << 16);
                    y3 += __uint_as_float(v.y & 0xFFFF0000u);
                }
            }
            int c0 = min(pe - pb, 64);
            for (int e = 0; e < c0; e += 4) {
                int slot = e + lg;
                int idx  = __shfl(sl, slot, 64);    // slot <= 63 always
                uint2 v  = xh2[idx * 16 + li];      // idx safe (0 if pad)
                if (slot < c0) {
                    y0 += __uint_as_float(v.x << 16);
                    y1 += __uint_as_float(v.x & 0xFFFF0000u);
                    y2 += __uint_as_float(v.y << 16);
                    y3 += __uint_as_float(v.y & 0xFFFF0000u);
                }
            }
            for (int b2 = pb + 64; b2 < pe; b2 += 64) {   // rare deg > 64
                int sl2 = (b2 + lane < pe) ? eidx[b2 + lane] : 0;
                int c2 = min(pe - b2, 64);
                for (int e = 0; e < c2; e += 4) {
                    int slot = e + lg;
                    int idx  = __shfl(sl2, slot, 64);
                    uint2 v  = xh2[idx * 16 + li];
                    if (slot < c2) {
                        y0 += __uint_as_float(v.x << 16);
                        y1 += __uint_as_float(v.x & 0xFFFF0000u);
                        y2 += __uint_as_float(v.y << 16);
                        y3 += __uint_as_float(v.y & 0xFFFF0000u);
                    }
                }
            }
        }
        // reduce the 4 edge-slot groups (lanes 16 apart hold same cols)
        y0 += __shfl_xor(y0, 16, 64); y0 += __shfl_xor(y0, 32, 64);
        y1 += __shfl_xor(y1, 16, 64); y1 += __shfl_xor(y1, 32, 64);
        y2 += __shfl_xor(y2, 16, 64); y2 += __shfl_xor(y2, 32, 64);
        y3 += __shfl_xor(y3, 16, 64); y3 += __shfl_xor(y3, 32, 64);

        // hi/lo bf16 split, packed 8B stores (conflict-free with AST stride)
        ushort4 ph, pl;
        ph.x = f2bf(y0); ph.y = f2bf(y1); ph.z = f2bf(y2); ph.w = f2bf(y3);
        pl.x = f2bf(y0 - bfu(ph.x)); pl.y = f2bf(y1 - bfu(ph.y));
        pl.z = f2bf(y2 - bfu(ph.z)); pl.w = f2bf(y3 - bfu(ph.w));
        int row = w * 16 + q;
        if (lg == 0)      *(ushort4*)&shAhi[row * AST + 4 * li] = ph;
        else if (lg == 1) *(ushort4*)&shAlo[row * AST + 4 * li] = pl;
    }

    // ---- MFMA phase: H(16x64) = (Ahi+Alo)(16x64) @ W(64x64), per wave ----
    int lr = lane & 15, lq = lane >> 4;
    const bf16x8 ah0 = *(const bf16x8*)&shAhi[(w * 16 + lr) * AST +  0 + 8 * lq];
    const bf16x8 ah1 = *(const bf16x8*)&shAhi[(w * 16 + lr) * AST + 32 + 8 * lq];
    const bf16x8 al0 = *(const bf16x8*)&shAlo[(w * 16 + lr) * AST +  0 + 8 * lq];
    const bf16x8 al1 = *(const bf16x8*)&shAlo[(w * 16 + lr) * AST + 32 + 8 * lq];

    f32x4 acc0 = {0.f,0.f,0.f,0.f}, acc1 = {0.f,0.f,0.f,0.f};
    f32x4 acc2 = {0.f,0.f,0.f,0.f}, acc3 = {0.f,0.f,0.f,0.f};
    #define DO_TILE(t, accv) { \
        bf16x8 b0 = *(const bf16x8*)&shW[(16*(t) + lr) * AST +  0 + 8 * lq]; \
        bf16x8 b1 = *(const bf16x8*)&shW[(16*(t) + lr) * AST + 32 + 8 * lq]; \
        accv = __builtin_amdgcn_mfma_f32_16x16x32_bf16(ah0, b0, accv, 0, 0, 0); \
        accv = __builtin_amdgcn_mfma_f32_16x16x32_bf16(al0, b0, accv, 0, 0, 0); \
        accv = __builtin_amdgcn_mfma_f32_16x16x32_bf16(ah1, b1, accv, 0, 0, 0); \
        accv = __builtin_amdgcn_mfma_f32_16x16x32_bf16(al1, b1, accv, 0, 0, 0); }
    DO_TILE(0, acc0) DO_TILE(1, acc1) DO_TILE(2, acc2) DO_TILE(3, acc3)
    #undef DO_TILE

    // ---- epilogue: bias+relu, scores, unshifted exp, per-graph pooling ----
    float bg0 = bg[lr], bg1 = bg[16 + lr], bg2 = bg[32 + lr], bg3 = bg[48 + lr];
    float wa0 = Wa[lr], wa1 = Wa[16 + lr], wa2 = Wa[32 + lr], wa3 = Wa[48 + lr];
    float ba0 = ba[0];

    float hv0[4], hv1[4], hv2[4], hv3[4];   // [t][r]: h[4*lq+r][16t+lr]
    #pragma unroll
    for (int r = 0; r < 4; ++r) {
        hv0[r] = fmaxf(acc0[r] + bg0, 0.f);
        hv1[r] = fmaxf(acc1[r] + bg1, 0.f);
        hv2[r] = fmaxf(acc2[r] + bg2, 0.f);
        hv3[r] = fmaxf(acc3[r] + bg3, 0.f);
    }
    float part[4];
    #pragma unroll
    for (int r = 0; r < 4; ++r)
        part[r] = hv0[r] * wa0 + hv1[r] * wa1 + hv2[r] * wa2 + hv3[r] * wa3;
    #pragma unroll
    for (int o = 1; o <= 8; o <<= 1) {
        #pragma unroll
        for (int r = 0; r < 4; ++r) part[r] += __shfl_xor(part[r], o, 64);
    }
    float ev[4]; int gidx[4];
    #pragma unroll
    for (int r = 0; r < 4; ++r) {
        int node = tile_base + 4 * lq + r;
        bool ok = node < N_NODES;
        ev[r]   = ok ? __expf(part[r] + ba0) : 0.f;   // unshifted exp (proven)
        gidx[r] = ok ? batch[node] : 0;
    }
    int gmin = batch[tile_base];
    int glast = tile_base + 15; if (glast >= N_NODES) glast = N_NODES - 1;
    int gmax = batch[glast];

    for (int gg = gmin; gg <= gmax; ++gg) {
        float w0 = (gidx[0] == gg) ? ev[0] : 0.f;
        float w1 = (gidx[1] == gg) ? ev[1] : 0.f;
        float w2 = (gidx[2] == gg) ? ev[2] : 0.f;
        float w3 = (gidx[3] == gg) ? ev[3] : 0.f;
        float p0 = w0 * hv0[0] + w1 * hv0[1] + w2 * hv0[2] + w3 * hv0[3];
        float p1 = w0 * hv1[0] + w1 * hv1[1] + w2 * hv1[2] + w3 * hv1[3];
        float p2 = w0 * hv2[0] + w1 * hv2[1] + w2 * hv2[2] + w3 * hv2[3];
        float p3 = w0 * hv3[0] + w1 * hv3[1] + w2 * hv3[2] + w3 * hv3[3];
        float dn = w0 + w1 + w2 + w3;
        #pragma unroll
        for (int o = 16; o <= 32; o <<= 1) {
            p0 += __shfl_xor(p0, o, 64); p1 += __shfl_xor(p1, o, 64);
            p2 += __shfl_xor(p2, o, 64); p3 += __shfl_xor(p3, o, 64);
            dn += __shfl_xor(dn, o, 64);
        }
        if (lq == 0) {
            atomicAdd(&out[gg * F +  0 + lr], p0);
            atomicAdd(&out[gg * F + 16 + lr], p1);
            atomicAdd(&out[gg * F + 32 + lr], p2);
            atomicAdd(&out[gg * F + 48 + lr], p3);
            if (lr == 0) atomicAdd(&denom[gg], dn);
        }
    }
}

// ---------- K4: out /= denom ----------
__global__ __launch_bounds__(BLK) void fin_kernel(
        float* __restrict__ out, const float* __restrict__ denom) {
    int i = blockIdx.x * BLK + threadIdx.x;
    if (i >= N_GRAPHS * F) return;
    float d = denom[i >> 6];
    out[i] = (d > 0.f) ? out[i] / d : 0.f;
}

extern "C" void kernel_launch(void* const* d_in, const int* in_sizes, int n_in,
                              void* d_out, int out_size, void* d_ws, size_t ws_size,
                              hipStream_t stream) {
    const float* x     = (const float*)d_in[0];
    const int*   ei    = (const int*)d_in[1];   // [2, N_EDGES]
    const int*   batch = (const int*)d_in[2];   // [N_NODES]
    const float* Wg    = (const float*)d_in[3];
    const float* bg    = (const float*)d_in[4];
    const float* Wa    = (const float*)d_in[5];
    const float* ba    = (const float*)d_in[6];
    float* out = (float*)d_out;

    const int* src = ei;
    const int* dst = ei + N_EDGES;

    // workspace layout (bytes), ~28.07 MB
    char* ws = (char*)d_ws;
    unsigned short* xh     = (unsigned short*)(ws);            // 12,800,000
    unsigned int*   pairs  = (unsigned int*)(ws + 12800000);   //  7,225,344
    int*            eidx   = (int*)(ws + 20025344);            //  7,225,344
    int*            nbeg   = (int*)(ws + 27250688);            //    400,000
    int*            nend   = (int*)(ws + 27652096);            //    400,000
    int*            balloc = (int*)(ws + 28053504);            //     12,544
    float*          denom  = (float*)(ws + 28066048);          //      1,024

    hipMemsetAsync(balloc, 0, NBUCK * BSTRIDE * sizeof(int), stream);
    bin_kernel        <<<GRID_PRE, BLK, 0, stream>>>(src, dst, pairs, balloc);
    sortcast_kernel   <<<GRID_PRE, SBLK, 0, stream>>>(x, xh, pairs, eidx,
                                                      nbeg, nend, balloc, out, denom);
    gather_mfma_kernel<<<NT_BLOCKS, BLK, 0, stream>>>(xh, nbeg, nend, eidx, batch,
                                                      Wg, bg, Wa, ba, out, denom);
    fin_kernel        <<<64, BLK, 0, stream>>>(out, denom);
}

// Round 9
// 193.565 us; speedup vs baseline: 1.1470x; 1.1362x over previous
//
#include <hip/hip_runtime.h>

#define N_NODES  100000
#define N_EDGES  1600000
#define N_GRAPHS 256
#define F        64

// ---------------------------------------------------------------------------
// R26. Evidence chain:
//  - R7/R8 (MFMA gather redesigns): 88.5 / 96.2 us — both SLOWER than R0's
//    80.3 us body. Redesign falsified; revert to R0 gather structure.
//  - NEW diagnosis of R0's 80 us: VGPR_Count=60 but wcol[64] needs 64 floats
//    -> compiler re-loads Wg from GLOBAL at each use (64 loads/node/wave,
//    no scratch writes, matches VALUBusy 47% + occupancy 35% + ~60MB excess
//    FETCH). Fix: W in LDS as packed bf16 pairs (8KB), [k/2][f] layout ->
//    conflict-free ds_read_b32, 32/node. bf16 W precision proven (R7/R8
//    passed 0.0625 with more rounding). Per-wave W preload gone -> NPW=13
//    re-enabled (R2's NPW-13 regression was the reload regime).
//  - Prep: R4's verbatim kernels (best measured total 179.3); zero_kernel
//    folded into memsetAsync + first cast block.
//  - R3: random 4B global writes cost a 64B line each -> scatter stays
//    LDS-staged/block-local.  - R1: no min-waves VGPR cap. - R6: no coop.
// ---------------------------------------------------------------------------

#define CHUNK    8192
#define NCHUNK   196                     // ceil(N_EDGES / CHUNK)
#define NBUCK    391                     // ceil(N_NODES / 256), bucket = dst>>8
#define BCAP     5120                    // bucket cap: mean 4092, +16 sigma

#define CAST_ELEMS   (N_NODES * F / 4)   // 1,600,000 float4
#define CAST_BLOCKS  ((CAST_ELEMS + 1023) / 1024)   // 1563
#define BC_BLOCKS    (NCHUNK + CAST_BLOCKS)         // 1759

__device__ __forceinline__ unsigned short f2bf(float f) {
    unsigned int u = __float_as_uint(f);
    u += 0x7FFFu + ((u >> 16) & 1u);
    return (unsigned short)(u >> 16);
}

// ---------- K1: bucket binning (blocks [0,196)) + x->bf16 cast (rest) ----------
// R4-verified body; first cast block additionally zeros out/denom.
__global__ __launch_bounds__(1024) void bin_cast_kernel(
        const int* __restrict__ src, const int* __restrict__ dst,
        const float* __restrict__ x, unsigned short* __restrict__ xh,
        unsigned int* __restrict__ pairs, int* __restrict__ balloc,
        float* __restrict__ out, float* __restrict__ denom) {
    int tid = threadIdx.x;
    int b   = blockIdx.x;

    if (b >= NCHUNK) {              // ---- streaming cast section ----
        if (b == NCHUNK) {          // fold: zero out/denom (consumed 2 kernels later)
            for (int i = tid; i < N_GRAPHS * F; i += 1024) out[i] = 0.f;
            if (tid < N_GRAPHS) denom[tid] = 0.f;
        }
        int i = (b - NCHUNK) * 1024 + tid;
        if (i < CAST_ELEMS) {
            float4 v = ((const float4*)x)[i];
            ushort4 o;
            o.x = f2bf(v.x); o.y = f2bf(v.y); o.z = f2bf(v.z); o.w = f2bf(v.w);
            ((ushort4*)xh)[i] = o;
        }
        return;
    }

    // ---- bin section ----
    __shared__ int hist[NBUCK];
    __shared__ int roffs[NBUCK];
    __shared__ int curs[NBUCK];
    __shared__ int bbase[NBUCK];
    __shared__ int wsum[16];
    __shared__ unsigned int   stage[CHUNK];    // 32 KB
    __shared__ unsigned short bstage[CHUNK];   // 16 KB

    int base = b * CHUNK;
    int m    = min(CHUNK, N_EDGES - base);
    int lane = tid & 63;
    int wv   = tid >> 6;

    for (int k = tid; k < NBUCK; k += 1024) hist[k] = 0;
    __syncthreads();

    int de[8], se[8];
    #pragma unroll
    for (int r = 0; r < 8; ++r) {
        int e = tid + r * 1024;
        if (e < m) {
            de[r] = dst[base + e];
            se[r] = src[base + e];
            atomicAdd(&hist[de[r] >> 8], 1);
        } else {
            de[r] = -1; se[r] = 0;
        }
    }
    __syncthreads();

    int v = (tid < NBUCK) ? hist[tid] : 0;
    #pragma unroll
    for (int o = 1; o < 64; o <<= 1) {
        int u = __shfl_up(v, o, 64);
        if (lane >= o) v += u;
    }
    if (lane == 63) wsum[wv] = v;
    __syncthreads();
    if (tid < 16) {
        int s = wsum[tid];
        #pragma unroll
        for (int o = 1; o < 16; o <<= 1) {
            int u = __shfl_up(s, o, 64);
            if (tid >= o) s += u;
        }
        wsum[tid] = s;
    }
    __syncthreads();
    if (wv > 0) v += wsum[wv - 1];
    if (tid < NBUCK) {
        int excl = v - hist[tid];
        roffs[tid] = excl;
        curs[tid]  = excl;
        if (hist[tid] > 0)    // one global atomic per (block,bucket) run
            bbase[tid] = tid * BCAP + atomicAdd(&balloc[tid], hist[tid]);
    }
    __syncthreads();

    #pragma unroll
    for (int r = 0; r < 8; ++r) {
        if (de[r] >= 0) {
            int bk  = de[r] >> 8;
            int pos = atomicAdd(&curs[bk], 1);
            stage[pos]  = ((unsigned)(de[r] & 255) << 17) | (unsigned)se[r];
            bstage[pos] = (unsigned short)bk;
        }
    }
    __syncthreads();

    for (int e = tid; e < m; e += 1024) {
        int bk = bstage[e];
        pairs[bbase[bk] + (e - roffs[bk])] = stage[e];
    }
}

// ---------- K2: per-bucket counting sort (contiguous input, in-place) ----------
// R4-verified body, untouched.
__global__ __launch_bounds__(512) void bucket_sort_kernel(
        unsigned int* __restrict__ pairs,      // in: pairs, out: eidx (aliased)
        const int* __restrict__ balloc,
        int* __restrict__ nbeg, int* __restrict__ nend) {
    __shared__ int hist[256];
    __shared__ int roffs[256];
    __shared__ int curs[256];
    __shared__ int wsum[8];
    __shared__ int sorted[BCAP];    // 20 KB

    int tid   = threadIdx.x;
    int b     = blockIdx.x;
    int lane  = tid & 63;
    int wv    = tid >> 6;
    int node0 = b << 8;
    int nn    = min(256, N_NODES - node0);
    int E     = balloc[b];
    int base  = b * BCAP;

    for (int k = tid; k < 256; k += 512) hist[k] = 0;
    __syncthreads();
    for (int i = tid; i < E; i += 512)
        atomicAdd(&hist[pairs[base + i] >> 17], 1);
    __syncthreads();

    int c = (tid < 256) ? hist[tid] : 0;
    int v = c;
    #pragma unroll
    for (int o = 1; o < 64; o <<= 1) {
        int u = __shfl_up(v, o, 64);
        if (lane >= o) v += u;
    }
    if (tid < 256 && lane == 63) wsum[wv] = v;
    __syncthreads();
    if (tid < 4) {
        int s = wsum[tid];
        int u = __shfl_up(s, 1, 64); if (tid >= 1) s += u;
        u     = __shfl_up(s, 2, 64); if (tid >= 2) s += u;
        wsum[tid] = s;
    }
    __syncthreads();
    if (tid < 256) {
        if (wv > 0) v += wsum[wv - 1];
        int excl = v - c;
        roffs[tid] = excl;
        curs[tid]  = excl;
        if (tid < nn) {
            nbeg[node0 + tid] = base + excl;
            nend[node0 + tid] = base + excl + c;
        }
    }
    __syncthreads();

    for (int i = tid; i < E; i += 512) {
        unsigned int p = pairs[base + i];
        int pos = atomicAdd(&curs[p >> 17], 1);
        sorted[pos] = (int)(p & 0x1FFFFu);
    }
    __syncthreads();
    for (int i = tid; i < E; i += 512)
        pairs[base + i] = (unsigned int)sorted[i];
}

// ---------- K3: fused gather+transform+pool (R0 body + LDS-bf16 weights) ----------
#define NODES_PER_WAVE 13
#define GT_NWAVES  ((N_NODES + NODES_PER_WAVE - 1) / NODES_PER_WAVE)   // 7693
#define GT_BLOCKS  ((GT_NWAVES + 3) / 4)                               // 1924

__device__ __forceinline__ float bfl(unsigned int u) { return __uint_as_float(u << 16); }
__device__ __forceinline__ float bfh(unsigned int u) { return __uint_as_float(u & 0xFFFF0000u); }

__global__ __launch_bounds__(256) void gather_pool_kernel(
        const unsigned short* __restrict__ xh,
        const int*   __restrict__ nbeg,
        const int*   __restrict__ nend,
        const int*   __restrict__ eidx,
        const int*   __restrict__ batch,
        const float* __restrict__ Wg,   // [64,64] (k, f)
        const float* __restrict__ bg,
        const float* __restrict__ Wa,
        const float* __restrict__ ba,
        float*       __restrict__ out_acc,   // [N_GRAPHS, F]
        float*       __restrict__ denom) {  // [N_GRAPHS]
    // W staged once per block: shw[kk*64+f] packs bf16(W[2kk][f]) (lo16)
    // and bf16(W[2kk+1][f]) (hi16). Reads are lane-consecutive 4B ->
    // conflict-free ds_read_b32. 8 KB total.
    __shared__ unsigned int shw[32 * 64];

    int tid  = threadIdx.x;
    int lane = tid & 63;
    for (int i = tid; i < 32 * 64; i += 256) {
        int kk = i >> 6, f = i & 63;
        unsigned int lo = (unsigned int)f2bf(Wg[(2 * kk)     * F + f]);
        unsigned int hi = (unsigned int)f2bf(Wg[(2 * kk + 1) * F + f]);
        shw[i] = lo | (hi << 16);
    }
    __syncthreads();   // only block-wide barrier

    int grp  = lane >> 3;   // 0..7: row within an 8-row gather batch
    int c    = lane & 7;    // 16-B chunk (8 bf16) within a row
    int waveId = blockIdx.x * 4 + (tid >> 6);
    int n0   = waveId * NODES_PER_WAVE;
    if (n0 >= N_NODES) return;          // idle tail waves (no later barriers)
    int nEnd = min(n0 + NODES_PER_WAVE, N_NODES);

    float bgl = bg[lane];
    float wal = Wa[lane];
    float ba0 = ba[0];

    const uint4* xh4 = (const uint4*)xh;     // row = 8 uint4

    int   cur_g = batch[n0];
    float accw  = 0.f;   // per-lane: sum e * h[lane]
    float denw  = 0.f;   // replicated: sum e

    int pb = nbeg[n0];
    int pe = nend[n0];
    int sl_cur = (pb + lane < pe) ? eidx[pb + lane] : 0;

    for (int n = n0; n < nEnd; ++n) {
        int start = pb, end = pe;
        int sl    = sl_cur;
        if (n + 1 < nEnd) {     // prefetch node n+1 while n's gathers fly
            pb = nbeg[n + 1];
            pe = nend[n + 1];
            sl_cur = (pb + lane < pe) ? eidx[pb + lane] : 0;
        }

        float a0=0.f,a1=0.f,a2=0.f,a3=0.f,a4=0.f,a5=0.f,a6=0.f,a7=0.f;
        {
            int jmax = end - start; if (jmax > 64) jmax = 64;
            for (int j = 0; j < jmax; j += 8) {
                int el = j + grp;
                int s  = __shfl(sl, el, 64);
                if (el < jmax) {
                    uint4 v = xh4[s * 8 + c];   // 16 B/lane, 8 rows/instr
                    a0 += bfl(v.x); a1 += bfh(v.x);
                    a2 += bfl(v.y); a3 += bfh(v.y);
                    a4 += bfl(v.z); a5 += bfh(v.z);
                    a6 += bfl(v.w); a7 += bfh(v.w);
                }
            }
        }
        for (int base2 = start + 64; base2 < end; base2 += 64) {  // deg > 64
            int jmax = end - base2; if (jmax > 64) jmax = 64;
            int sl2 = (base2 + lane < end) ? eidx[base2 + lane] : 0;
            for (int j = 0; j < jmax; j += 8) {
                int el = j + grp;
                int s  = __shfl(sl2, el, 64);
                if (el < jmax) {
                    uint4 v = xh4[s * 8 + c];
                    a0 += bfl(v.x); a1 += bfh(v.x);
                    a2 += bfl(v.y); a3 += bfh(v.y);
                    a4 += bfl(v.z); a5 += bfh(v.z);
                    a6 += bfl(v.w); a7 += bfh(v.w);
                }
            }
        }
        #pragma unroll
        for (int o = 8; o <= 32; o <<= 1) {
            a0 += __shfl_xor(a0, o, 64); a1 += __shfl_xor(a1, o, 64);
            a2 += __shfl_xor(a2, o, 64); a3 += __shfl_xor(a3, o, 64);
            a4 += __shfl_xor(a4, o, 64); a5 += __shfl_xor(a5, o, 64);
            a6 += __shfl_xor(a6, o, 64); a7 += __shfl_xor(a7, o, 64);
        }
        {
            uint4 v = xh4[n * 8 + c];   // self row
            a0 += bfl(v.x); a1 += bfh(v.x);
            a2 += bfl(v.y); a3 += bfh(v.y);
            a4 += bfl(v.z); a5 += bfh(v.z);
            a6 += bfl(v.w); a7 += bfh(v.w);
        }

        // matmul: h[lane] = sum_k y[k] * W[k][lane].
        // y[8*kk8+i] lives in re[i] of lane kk8 (c == kk8 group).
        // Weights from LDS: pair kk = 4*kk8 + i/2 -> 32 conflict-free b32.
        float re[8] = {a0,a1,a2,a3,a4,a5,a6,a7};
        float q0=0.f,q1=0.f,q2=0.f,q3=0.f,q4=0.f,q5=0.f,q6=0.f,q7=0.f;
        #pragma unroll
        for (int kk8 = 0; kk8 < 8; ++kk8) {
            float y0 = __int_as_float(__builtin_amdgcn_readlane(__float_as_int(re[0]), kk8));
            float y1 = __int_as_float(__builtin_amdgcn_readlane(__float_as_int(re[1]), kk8));
            float y2 = __int_as_float(__builtin_amdgcn_readlane(__float_as_int(re[2]), kk8));
            float y3 = __int_as_float(__builtin_amdgcn_readlane(__float_as_int(re[3]), kk8));
            float y4 = __int_as_float(__builtin_amdgcn_readlane(__float_as_int(re[4]), kk8));
            float y5 = __int_as_float(__builtin_amdgcn_readlane(__float_as_int(re[5]), kk8));
            float y6 = __int_as_float(__builtin_amdgcn_readlane(__float_as_int(re[6]), kk8));
            float y7 = __int_as_float(__builtin_amdgcn_readlane(__float_as_int(re[7]), kk8));
            unsigned int u0 = shw[(4 * kk8 + 0) * 64 + lane];
            unsigned int u1 = shw[(4 * kk8 + 1) * 64 + lane];
            unsigned int u2 = shw[(4 * kk8 + 2) * 64 + lane];
            unsigned int u3 = shw[(4 * kk8 + 3) * 64 + lane];
            q0 += y0 * bfl(u0); q1 += y1 * bfh(u0);
            q2 += y2 * bfl(u1); q3 += y3 * bfh(u1);
            q4 += y4 * bfl(u2); q5 += y5 * bfh(u2);
            q6 += y6 * bfl(u3); q7 += y7 * bfh(u3);
        }
        float hv = ((q0 + q1) + (q2 + q3)) + ((q4 + q5) + (q6 + q7)) + bgl;
        hv = hv > 0.f ? hv : 0.f;

        float p = hv * wal;
        #pragma unroll
        for (int o = 32; o > 0; o >>= 1)
            p += __shfl_down(p, o, 64);
        float s = __int_as_float(__builtin_amdgcn_readlane(__float_as_int(p), 0)) + ba0;
        float e = __expf(s);    // unshifted: softmax ratio is shift-invariant

        int g = batch[n];       // wave-uniform
        if (g != cur_g) {
            atomicAdd(&out_acc[cur_g * F + lane], accw);
            if (lane == 0) atomicAdd(&denom[cur_g], denw);
            accw = 0.f; denw = 0.f; cur_g = g;
        }
        accw += e * hv;
        denw += e;
    }
    atomicAdd(&out_acc[cur_g * F + lane], accw);
    if (lane == 0) atomicAdd(&denom[cur_g], denw);
}

// ---------- K4: out /= denom ----------
__global__ __launch_bounds__(256) void fin_kernel(
        float* __restrict__ out, const float* __restrict__ denom) {
    int i = blockIdx.x * 256 + threadIdx.x;
    if (i >= N_GRAPHS * F) return;
    float d = denom[i >> 6];
    out[i] = (d > 0.f) ? out[i] / d : 0.f;
}

extern "C" void kernel_launch(void* const* d_in, const int* in_sizes, int n_in,
                              void* d_out, int out_size, void* d_ws, size_t ws_size,
                              hipStream_t stream) {
    const float* x     = (const float*)d_in[0];
    const int*   ei    = (const int*)d_in[1];   // [2, N_EDGES]
    const int*   batch = (const int*)d_in[2];   // [N_NODES]
    const float* Wg    = (const float*)d_in[3];
    const float* bg    = (const float*)d_in[4];
    const float* Wa    = (const float*)d_in[5];
    const float* ba    = (const float*)d_in[6];
    float* out = (float*)d_out;

    const int* src = ei;
    const int* dst = ei + N_EDGES;

    // workspace layout (bytes)
    char* ws = (char*)d_ws;
    unsigned short* xh     = (unsigned short*)(ws);            // 12,800,000
    unsigned int*   pairs  = (unsigned int*)(ws + 12800000);   //  8,007,680 (NBUCK*BCAP*4; doubles as eidx)
    int*            nbeg   = (int*)(ws + 20807680);            //    400,000
    int*            nend   = (int*)(ws + 21207808);            //    400,000
    int*            balloc = (int*)(ws + 21607936);            //      2,048
    float*          denom  = (float*)(ws + 21610240);          //      1,024

    hipMemsetAsync(balloc, 0, NBUCK * sizeof(int), stream);
    bin_cast_kernel   <<<BC_BLOCKS, 1024, 0, stream>>>(src, dst, x, xh, pairs,
                                                       balloc, out, denom);
    bucket_sort_kernel<<<NBUCK, 512, 0, stream>>>(pairs, balloc, nbeg, nend);
    gather_pool_kernel<<<GT_BLOCKS, 256, 0, stream>>>(
        xh, nbeg, nend, (const int*)pairs, batch, Wg, bg, Wa, ba, out, denom);
    fin_kernel        <<<64, 256, 0, stream>>>(out, denom);
}